// Round 4
// baseline (262.175 us; speedup 1.0000x reference)
//
#include <hip/hip_runtime.h>

// out[b, t, n, :] = x[b, (t - shift[n]) % 16, n, :]
// x: (B=16, T=16, N=196, c=768) fp32, contiguous. Pure gather along T.
//
// shift[n] closed form (m=1): w=n%7, h=n/7, a=w%3, b=h%3:
//   (0,0)->-4 (0,1)->1 (0,2)->2
//   (1,0)->-1 (1,1)-> (n==8 ? 0 : -1)   // sticky inv_state: only i=8 sees inv==0
//   (1,2)->3  (2,0)->-2 (2,1)->-3 (2,2)->4
//
// R3: linear-output grid-stride copy (the structure that hits 6.3 TB/s in
// m13), gather on the read side. Each block owns a contiguous 2048-f4 (32 KB)
// output tile; each thread handles 8 f4s strided by 256 (coalesced per
// instruction). Source index decoded per-f4 with constant-divide magic muls
// (~20 VALU ops/f4 — 20x headroom vs the 10.3 B/cy/CU memory rate).
// Plain loads (x is restore-warm in L2/L3), nontemporal stores (out is
// written once, never re-read by us).

typedef float f4 __attribute__((ext_vector_type(4)));

#define TOTAL_F4 9633792u       // 16*16*196*192
#define TILE_F4  2048u          // 256 threads * 8 f4
#define NBLOCKS  4704u          // TOTAL_F4 / TILE_F4, exact

__global__ __launch_bounds__(256) void Rand2dPatchShift_kernel(
        const f4* __restrict__ x, f4* __restrict__ out) {
    const unsigned base = blockIdx.x * TILE_F4 + threadIdx.x;

    unsigned srcIdx[8];
#pragma unroll
    for (int k = 0; k < 8; ++k) {
        const unsigned idx  = base + (unsigned)k * 256u;
        const unsigned lane = idx % 192u;          // channel f4 lane
        const unsigned r    = idx / 192u;
        const unsigned n    = r % 196u;
        const unsigned q    = r / 196u;
        const unsigned t    = q & 15u;
        const unsigned b    = q >> 4;

        const unsigned w  = n % 7u;
        const unsigned h  = n / 7u;
        const unsigned a3 = w % 3u;
        const unsigned b3 = h % 3u;
        int s;
        if (a3 == 0u)      s = (b3 == 0u) ? -4 : (b3 == 1u ? 1 : 2);
        else if (a3 == 1u) s = (b3 == 0u) ? -1 : (b3 == 1u ? ((n == 8u) ? 0 : -1) : 3);
        else               s = (b3 == 0u) ? -2 : (b3 == 1u ? -3 : 4);

        const unsigned tsrc = (unsigned)(((int)t - s) & 15);
        srcIdx[k] = ((b * 16u + tsrc) * 196u + n) * 192u + lane;
    }

    f4 v[8];
#pragma unroll
    for (int k = 0; k < 8; ++k) v[k] = x[srcIdx[k]];
#pragma unroll
    for (int k = 0; k < 8; ++k)
        __builtin_nontemporal_store(v[k], &out[base + (unsigned)k * 256u]);
}

extern "C" void kernel_launch(void* const* d_in, const int* in_sizes, int n_in,
                              void* d_out, int out_size, void* d_ws, size_t ws_size,
                              hipStream_t stream) {
    const f4* x = (const f4*)d_in[0];
    f4* out = (f4*)d_out;

    Rand2dPatchShift_kernel<<<dim3(NBLOCKS), dim3(256), 0, stream>>>(x, out);
}